// Round 15
// baseline (12403.773 us; speedup 1.0000x reference)
//
#include <hip/hip_runtime.h>

// KANSpikingNeuron — exact-arithmetic, v4: occupancy 2->3 blocks/CU.
// Proven chain (r11): per element, 8 flat K-blocks of 512 ascending; serial
// FMA chain per block; fp32 ascending merges (= global fp32 RMW accumulate);
// separate fp32 bias add; relu (fp32 h) / >0 threshold.
// r14->r15: __launch_bounds__(256,3) (LDS 48KB -> 3 blocks/CU fits 144/160KB,
// VGPR cap 170 >= 120) + epilogue Cprev/bias prefetch before last tile.

constexpr int B_TOT = 8192, IN = 4096, HID = 4096, OUT = 4096;
constexpr int BM = 128, BN = 256, BK = 32;
constexpr int KBLK = 512;
constexpr int NT = KBLK / BK;   // 16 tiles per pass

// MODE: 0 = store blk; 1 = store fadd(prev, blk); 2 = final: bias + epilogue
template <int MODE, bool RELU>
__global__ __launch_bounds__(256, 3)
void gemm_pass(const float* __restrict__ A, const float* __restrict__ W,
               const float* __restrict__ bias, const float* Cprev,
               float* Cout, int N, int K, int k0) {
#pragma clang fp contract(off)
  __shared__ float As[BK][BM];      // 16 KB, k-major
  __shared__ float Ws[BK * BN];     // 32 KB, k-major, chunk-interleaved

  const int tid = threadIdx.x;
  const int tc = tid & 15;          // 16 cols of 16
  const int tr = tid >> 4;          // 16 rows of 8
  const int bm = blockIdx.y * BM;
  const int bn = blockIdx.x * BN;

  const int srow = tid >> 1;
  const int kb = (tid & 1) * 16;
  // W col c -> word ((c>>2)&3)*64 + (c>>4)*4 + (c&3); reads 2-way = free
  const int cw = ((tid >> 2) & 3) * 64 + (tid >> 4) * 4 + (tid & 3);

  const float* arow = A + (size_t)(bm + srow) * K + (k0 + kb);
  const float* wrow = W + (size_t)(bn + tid) * K + k0;

  float4 av[4], wv[8];
#define PREFETCH(t)                                                        \
  {                                                                        \
    _Pragma("unroll") for (int u = 0; u < 4; ++u)                          \
        av[u] = *reinterpret_cast<const float4*>(arow + (t)*BK + 4 * u);   \
    _Pragma("unroll") for (int u = 0; u < 8; ++u)                          \
        wv[u] = *reinterpret_cast<const float4*>(wrow + (t)*BK + 4 * u);   \
  }
#define STAGE_WRITE()                                                      \
  {                                                                        \
    _Pragma("unroll") for (int u = 0; u < 4; ++u) {                        \
      const float va[4] = {av[u].x, av[u].y, av[u].z, av[u].w};            \
      _Pragma("unroll") for (int e = 0; e < 4; ++e)                        \
          As[kb + 4 * u + e][srow] = va[e];                                \
    }                                                                      \
    _Pragma("unroll") for (int u = 0; u < 8; ++u) {                        \
      const float vw[4] = {wv[u].x, wv[u].y, wv[u].z, wv[u].w};            \
      _Pragma("unroll") for (int e = 0; e < 4; ++e)                        \
          Ws[(4 * u + e) * BN + cw] = vw[e];                               \
    }                                                                      \
  }

  float blk[8][16];
#pragma unroll
  for (int i = 0; i < 8; ++i)
#pragma unroll
    for (int j = 0; j < 16; ++j) blk[i][j] = 0.0f;

  PREFETCH(0)
  STAGE_WRITE()
  __syncthreads();

  // epilogue prefetch registers (issued before the last tile's compute)
  float4 cv[8][4];
  float bs[16];

  for (int t = 0; t < NT; ++t) {
    if (t + 1 < NT) {
      PREFETCH(t + 1)                       // HBM latency hides under compute
    } else {
      // last tile: issue epilogue loads now, latency hides under 32 kk
      if constexpr (MODE >= 1) {
#pragma unroll
        for (int i = 0; i < 8; ++i) {
          const size_t base =
              (size_t)(bm + tr * 8 + i) * N + bn + tc * 16;
#pragma unroll
          for (int q = 0; q < 4; ++q)
            cv[i][q] = *reinterpret_cast<const float4*>(Cprev + base + 4 * q);
        }
      }
      if constexpr (MODE == 2) {
#pragma unroll
        for (int j = 0; j < 16; ++j) bs[j] = bias[bn + tc * 16 + j];
      }
    }
#pragma unroll 2
    for (int kk = 0; kk < BK; ++kk) {
      float a[8], w[16];
      *reinterpret_cast<float4*>(&a[0]) =
          *reinterpret_cast<const float4*>(&As[kk][tr * 8]);
      *reinterpret_cast<float4*>(&a[4]) =
          *reinterpret_cast<const float4*>(&As[kk][tr * 8 + 4]);
#pragma unroll
      for (int q = 0; q < 4; ++q)
        *reinterpret_cast<float4*>(&w[4 * q]) =
            *reinterpret_cast<const float4*>(&Ws[kk * BN + q * 64 + tc * 4]);
#pragma unroll
      for (int i = 0; i < 8; ++i)
#pragma unroll
        for (int j = 0; j < 16; ++j)
          blk[i][j] = __fmaf_rn(a[i], w[j], blk[i][j]);   // k ascending chain
    }
    __syncthreads();                        // all reads of this tile done
    if (t + 1 < NT) {
      STAGE_WRITE()
      __syncthreads();
    }
  }
#undef PREFETCH
#undef STAGE_WRITE

  // ---- epilogue (loads already in flight) ----
#pragma unroll
  for (int i = 0; i < 8; ++i) {
    const size_t base = (size_t)(bm + tr * 8 + i) * N + bn + tc * 16;
    float o[16];
#pragma unroll
    for (int j = 0; j < 16; ++j) {
      float v = blk[i][j];
      if constexpr (MODE >= 1) {
        const float pj = (&cv[i][j >> 2].x)[j & 3];
        v = __fadd_rn(pj, v);               // ascending block merge
      }
      if constexpr (MODE == 2) {
        v = __fadd_rn(v, bs[j]);            // separate fp32 bias add
        o[j] = RELU ? (v > 0.0f ? v : 0.0f) : (v > 0.0f ? 1.0f : 0.0f);
      } else {
        o[j] = v;                           // fp32 partial, exact
      }
    }
#pragma unroll
    for (int q = 0; q < 4; ++q)
      *reinterpret_cast<float4*>(Cout + base + 4 * q) =
          make_float4(o[4 * q], o[4 * q + 1], o[4 * q + 2], o[4 * q + 3]);
  }
}

static void run_layer(const float* A, const float* W, const float* bias,
                      float* partial, float* dest, bool relu, int rows,
                      int N, int K, hipStream_t stream) {
  const dim3 blk(256);
  const dim3 g(N / BN, rows / BM);
  const int NP = K / KBLK;   // 8 passes
  for (int p = 0; p < NP; ++p) {
    const int k0 = p * KBLK;
    if (p == 0) {
      gemm_pass<0, false><<<g, blk, 0, stream>>>(A, W, bias, nullptr, partial,
                                                 N, K, k0);
    } else if (p < NP - 1) {
      gemm_pass<1, false><<<g, blk, 0, stream>>>(A, W, bias, partial, partial,
                                                 N, K, k0);
    } else if (relu) {
      gemm_pass<2, true><<<g, blk, 0, stream>>>(A, W, bias, partial, dest,
                                                N, K, k0);
    } else {
      gemm_pass<2, false><<<g, blk, 0, stream>>>(A, W, bias, partial, dest,
                                                 N, K, k0);
    }
  }
}

extern "C" void kernel_launch(void* const* d_in, const int* in_sizes, int n_in,
                              void* d_out, int out_size, void* d_ws, size_t ws_size,
                              hipStream_t stream) {
  const float* x  = (const float*)d_in[0];
  const float* W1 = (const float*)d_in[1];
  const float* b1 = (const float*)d_in[2];
  const float* W2 = (const float*)d_in[3];
  const float* b2 = (const float*)d_in[4];
  float* out = (float*)d_out;

  size_t rows = ws_size / ((size_t)2 * HID * sizeof(float));
  rows = (rows / BM) * BM;
  if (rows > (size_t)B_TOT) rows = B_TOT;
  if (rows < BM) rows = BM;

  float* h   = (float*)d_ws;                         // rows x HID
  float* y2p = h + (size_t)rows * HID;               // rows x OUT

  for (int m0 = 0; m0 < B_TOT; m0 += (int)rows) {
    const int mrows = (B_TOT - m0 < (int)rows) ? (B_TOT - m0) : (int)rows;
    run_layer(x + (size_t)m0 * IN, W1, b1, h, h, true, mrows, HID, IN, stream);
    run_layer(h, W2, b2, y2p, out + (size_t)m0 * OUT, false, mrows, OUT, HID,
              stream);
  }
}

// Round 16
// 8655.145 us; speedup vs baseline: 1.4331x; 1.4331x over previous
//
#include <hip/hip_runtime.h>

// KANSpikingNeuron — exact-arithmetic, v5: r14 structure + 3 blocks/CU ONLY.
// r15's regression was the epilogue cv[8][4] prefetch (128 VGPR held across
// the last compute tile) -> accumulator spill to scratch (VGPR 84, 2.7GB/pass
// scratch traffic). Reverted. Single change vs r14: __launch_bounds__(256,3).
// Proven chain (r11): 8 flat K-blocks of 512 ascending; serial FMA chain per
// block; fp32 ascending merges (= global fp32 RMW); separate bias add; relu /
// >0 threshold. Arithmetic bit-identical.

constexpr int B_TOT = 8192, IN = 4096, HID = 4096, OUT = 4096;
constexpr int BM = 128, BN = 256, BK = 32;
constexpr int KBLK = 512;
constexpr int NT = KBLK / BK;   // 16 tiles per pass

// MODE: 0 = store blk; 1 = store fadd(prev, blk); 2 = final: bias + epilogue
template <int MODE, bool RELU>
__global__ __launch_bounds__(256, 3)
void gemm_pass(const float* __restrict__ A, const float* __restrict__ W,
               const float* __restrict__ bias, const float* Cprev,
               float* Cout, int N, int K, int k0) {
#pragma clang fp contract(off)
  __shared__ float As[BK][BM];      // 16 KB, k-major
  __shared__ float Ws[BK * BN];     // 32 KB, k-major, chunk-interleaved

  const int tid = threadIdx.x;
  const int tc = tid & 15;          // 16 cols of 16
  const int tr = tid >> 4;          // 16 rows of 8
  const int bm = blockIdx.y * BM;
  const int bn = blockIdx.x * BN;

  const int srow = tid >> 1;
  const int kb = (tid & 1) * 16;
  // W col c -> word ((c>>2)&3)*64 + (c>>4)*4 + (c&3); reads 2-way = free
  const int cw = ((tid >> 2) & 3) * 64 + (tid >> 4) * 4 + (tid & 3);

  const float* arow = A + (size_t)(bm + srow) * K + (k0 + kb);
  const float* wrow = W + (size_t)(bn + tid) * K + k0;

  float4 av[4], wv[8];
#define PREFETCH(t)                                                        \
  {                                                                        \
    _Pragma("unroll") for (int u = 0; u < 4; ++u)                          \
        av[u] = *reinterpret_cast<const float4*>(arow + (t)*BK + 4 * u);   \
    _Pragma("unroll") for (int u = 0; u < 8; ++u)                          \
        wv[u] = *reinterpret_cast<const float4*>(wrow + (t)*BK + 4 * u);   \
  }
#define STAGE_WRITE()                                                      \
  {                                                                        \
    _Pragma("unroll") for (int u = 0; u < 4; ++u) {                        \
      const float va[4] = {av[u].x, av[u].y, av[u].z, av[u].w};            \
      _Pragma("unroll") for (int e = 0; e < 4; ++e)                        \
          As[kb + 4 * u + e][srow] = va[e];                                \
    }                                                                      \
    _Pragma("unroll") for (int u = 0; u < 8; ++u) {                        \
      const float vw[4] = {wv[u].x, wv[u].y, wv[u].z, wv[u].w};            \
      _Pragma("unroll") for (int e = 0; e < 4; ++e)                        \
          Ws[(4 * u + e) * BN + cw] = vw[e];                               \
    }                                                                      \
  }

  float blk[8][16];
#pragma unroll
  for (int i = 0; i < 8; ++i)
#pragma unroll
    for (int j = 0; j < 16; ++j) blk[i][j] = 0.0f;

  PREFETCH(0)
  STAGE_WRITE()
  __syncthreads();

  for (int t = 0; t < NT; ++t) {
    if (t + 1 < NT) PREFETCH(t + 1)        // HBM latency hides under compute
#pragma unroll 2
    for (int kk = 0; kk < BK; ++kk) {
      float a[8], w[16];
      *reinterpret_cast<float4*>(&a[0]) =
          *reinterpret_cast<const float4*>(&As[kk][tr * 8]);
      *reinterpret_cast<float4*>(&a[4]) =
          *reinterpret_cast<const float4*>(&As[kk][tr * 8 + 4]);
#pragma unroll
      for (int q = 0; q < 4; ++q)
        *reinterpret_cast<float4*>(&w[4 * q]) =
            *reinterpret_cast<const float4*>(&Ws[kk * BN + q * 64 + tc * 4]);
#pragma unroll
      for (int i = 0; i < 8; ++i)
#pragma unroll
        for (int j = 0; j < 16; ++j)
          blk[i][j] = __fmaf_rn(a[i], w[j], blk[i][j]);   // k ascending chain
    }
    __syncthreads();                        // all reads of this tile done
    if (t + 1 < NT) {
      STAGE_WRITE()
      __syncthreads();
    }
  }
#undef PREFETCH
#undef STAGE_WRITE

  // ---- epilogue ----
  float bs[16];
  if constexpr (MODE == 2) {
#pragma unroll
    for (int j = 0; j < 16; ++j) bs[j] = bias[bn + tc * 16 + j];
  }
#pragma unroll
  for (int i = 0; i < 8; ++i) {
    const size_t base = (size_t)(bm + tr * 8 + i) * N + bn + tc * 16;
    float4 cv[4];
    if constexpr (MODE >= 1) {
#pragma unroll
      for (int q = 0; q < 4; ++q)
        cv[q] = *reinterpret_cast<const float4*>(Cprev + base + 4 * q);
    }
    float o[16];
#pragma unroll
    for (int j = 0; j < 16; ++j) {
      float v = blk[i][j];
      if constexpr (MODE >= 1) {
        const float pj = (&cv[j >> 2].x)[j & 3];
        v = __fadd_rn(pj, v);               // ascending block merge
      }
      if constexpr (MODE == 2) {
        v = __fadd_rn(v, bs[j]);            // separate fp32 bias add
        o[j] = RELU ? (v > 0.0f ? v : 0.0f) : (v > 0.0f ? 1.0f : 0.0f);
      } else {
        o[j] = v;                           // fp32 partial, exact
      }
    }
#pragma unroll
    for (int q = 0; q < 4; ++q)
      *reinterpret_cast<float4*>(Cout + base + 4 * q) =
          make_float4(o[4 * q], o[4 * q + 1], o[4 * q + 2], o[4 * q + 3]);
  }
}

static void run_layer(const float* A, const float* W, const float* bias,
                      float* partial, float* dest, bool relu, int rows,
                      int N, int K, hipStream_t stream) {
  const dim3 blk(256);
  const dim3 g(N / BN, rows / BM);
  const int NP = K / KBLK;   // 8 passes
  for (int p = 0; p < NP; ++p) {
    const int k0 = p * KBLK;
    if (p == 0) {
      gemm_pass<0, false><<<g, blk, 0, stream>>>(A, W, bias, nullptr, partial,
                                                 N, K, k0);
    } else if (p < NP - 1) {
      gemm_pass<1, false><<<g, blk, 0, stream>>>(A, W, bias, partial, partial,
                                                 N, K, k0);
    } else if (relu) {
      gemm_pass<2, true><<<g, blk, 0, stream>>>(A, W, bias, partial, dest,
                                                N, K, k0);
    } else {
      gemm_pass<2, false><<<g, blk, 0, stream>>>(A, W, bias, partial, dest,
                                                 N, K, k0);
    }
  }
}

extern "C" void kernel_launch(void* const* d_in, const int* in_sizes, int n_in,
                              void* d_out, int out_size, void* d_ws, size_t ws_size,
                              hipStream_t stream) {
  const float* x  = (const float*)d_in[0];
  const float* W1 = (const float*)d_in[1];
  const float* b1 = (const float*)d_in[2];
  const float* W2 = (const float*)d_in[3];
  const float* b2 = (const float*)d_in[4];
  float* out = (float*)d_out;

  size_t rows = ws_size / ((size_t)2 * HID * sizeof(float));
  rows = (rows / BM) * BM;
  if (rows > (size_t)B_TOT) rows = B_TOT;
  if (rows < BM) rows = BM;

  float* h   = (float*)d_ws;                         // rows x HID
  float* y2p = h + (size_t)rows * HID;               // rows x OUT

  for (int m0 = 0; m0 < B_TOT; m0 += (int)rows) {
    const int mrows = (B_TOT - m0 < (int)rows) ? (B_TOT - m0) : (int)rows;
    run_layer(x + (size_t)m0 * IN, W1, b1, h, h, true, mrows, HID, IN, stream);
    run_layer(h, W2, b2, y2p, out + (size_t)m0 * OUT, false, mrows, OUT, HID,
              stream);
  }
}

// Round 17
// 6217.504 us; speedup vs baseline: 1.9950x; 1.3921x over previous
//
#include <hip/hip_runtime.h>

// KANSpikingNeuron — exact-arithmetic, v6: LDS double-buffer, 1 barrier/tile.
// Proven chain (r11): 8 flat K-blocks of 512 ascending; serial FMA chain per
// block; fp32 ascending merges (= global fp32 RMW); separate bias add; relu /
// >0 threshold. Arithmetic bit-identical to r14 (k strictly ascending).
// r16 lesson: __launch_bounds__(256,3) caps VGPR at ~85 -> spill; stay (256,2).
// r14 lesson: barrier->stage->barrier phase = 143us/pass stall. Fix: BK=16,
// dbuf A/W (48KB total, same as r14), write tile t+1 into opposite buffer
// while other waves compute tile t; ONE barrier per tile.

constexpr int B_TOT = 8192, IN = 4096, HID = 4096, OUT = 4096;
constexpr int BM = 128, BN = 256, BK = 16;
constexpr int KBLK = 512;
constexpr int NT = KBLK / BK;   // 32 tiles per pass

// MODE: 0 = store blk; 1 = store fadd(prev, blk); 2 = final: bias + epilogue
template <int MODE, bool RELU>
__global__ __launch_bounds__(256, 2)
void gemm_pass(const float* __restrict__ A, const float* __restrict__ W,
               const float* __restrict__ bias, const float* Cprev,
               float* Cout, int N, int K, int k0) {
#pragma clang fp contract(off)
  __shared__ float As[2][BK][BM];   // 2 x 8 KB
  __shared__ float Ws[2][BK * BN];  // 2 x 16 KB, chunk-interleaved

  const int tid = threadIdx.x;
  const int tc = tid & 15;          // 16 cols of 16
  const int tr = tid >> 4;          // 16 rows of 8
  const int bm = blockIdx.y * BM;
  const int bn = blockIdx.x * BN;

  const int srow = tid >> 1;            // A staging row 0..127
  const int kbA = (tid & 1) * 8;        // A staging k-base (8 floats)
  // W col c -> word ((c>>2)&3)*64 + (c>>4)*4 + (c&3); float4 reads 2-way free
  const int cw = ((tid >> 2) & 3) * 64 + (tid >> 4) * 4 + (tid & 3);

  const float* arow = A + (size_t)(bm + srow) * K + (k0 + kbA);
  const float* wrow = W + (size_t)(bn + tid) * K + k0;

  float4 av[2], wv[4];                  // tile-in-flight registers (24 VGPR)
#define PREFETCH(t)                                                         \
  {                                                                         \
    _Pragma("unroll") for (int u = 0; u < 2; ++u)                           \
        av[u] = *reinterpret_cast<const float4*>(arow + (t)*BK + 4 * u);    \
    _Pragma("unroll") for (int u = 0; u < 4; ++u)                           \
        wv[u] = *reinterpret_cast<const float4*>(wrow + (t)*BK + 4 * u);    \
  }
#define STAGE_WRITE(B)                                                      \
  {                                                                         \
    _Pragma("unroll") for (int u = 0; u < 2; ++u) {                         \
      const float va[4] = {av[u].x, av[u].y, av[u].z, av[u].w};             \
      _Pragma("unroll") for (int e = 0; e < 4; ++e)                         \
          As[B][kbA + 4 * u + e][srow] = va[e];                             \
    }                                                                       \
    _Pragma("unroll") for (int u = 0; u < 4; ++u) {                         \
      const float vw[4] = {wv[u].x, wv[u].y, wv[u].z, wv[u].w};             \
      _Pragma("unroll") for (int e = 0; e < 4; ++e)                         \
          Ws[B][(4 * u + e) * BN + cw] = vw[e];                             \
    }                                                                       \
  }
#define COMPUTE(B)                                                          \
  _Pragma("unroll 2") for (int kk = 0; kk < BK; ++kk) {                     \
    float a[8], w[16];                                                      \
    *reinterpret_cast<float4*>(&a[0]) =                                     \
        *reinterpret_cast<const float4*>(&As[B][kk][tr * 8]);               \
    *reinterpret_cast<float4*>(&a[4]) =                                     \
        *reinterpret_cast<const float4*>(&As[B][kk][tr * 8 + 4]);           \
    _Pragma("unroll") for (int q = 0; q < 4; ++q)                           \
        *reinterpret_cast<float4*>(&w[4 * q]) =                             \
            *reinterpret_cast<const float4*>(                               \
                &Ws[B][kk * BN + q * 64 + tc * 4]);                         \
    _Pragma("unroll") for (int i = 0; i < 8; ++i)                           \
        _Pragma("unroll") for (int j = 0; j < 16; ++j)                      \
            blk[i][j] = __fmaf_rn(a[i], w[j], blk[i][j]);                   \
  }

  float blk[8][16];
#pragma unroll
  for (int i = 0; i < 8; ++i)
#pragma unroll
    for (int j = 0; j < 16; ++j) blk[i][j] = 0.0f;

  // prologue: buf0 <- tile0; R <- tile1
  PREFETCH(0)
  STAGE_WRITE(0)
  PREFETCH(1)
  __syncthreads();

  // steady state, 2 tiles per iteration (static buffer indices)
  for (int t = 0; t < NT; t += 2) {
    // tile t (even) from buf0; write tile t+1 into buf1; prefetch t+2
    COMPUTE(0)
    STAGE_WRITE(1)                 // R holds tile t+1
    if (t + 2 < NT) PREFETCH(t + 2)
    __syncthreads();
    // tile t+1 (odd) from buf1; write tile t+2 into buf0; prefetch t+3
    COMPUTE(1)
    if (t + 2 < NT) {
      STAGE_WRITE(0)               // R holds tile t+2
      if (t + 3 < NT) PREFETCH(t + 3)
    }
    __syncthreads();
  }
#undef PREFETCH
#undef STAGE_WRITE
#undef COMPUTE

  // ---- epilogue ----
  float bs[16];
  if constexpr (MODE == 2) {
#pragma unroll
    for (int j = 0; j < 16; ++j) bs[j] = bias[bn + tc * 16 + j];
  }
#pragma unroll
  for (int i = 0; i < 8; ++i) {
    const size_t base = (size_t)(bm + tr * 8 + i) * N + bn + tc * 16;
    float4 cv[4];
    if constexpr (MODE >= 1) {
#pragma unroll
      for (int q = 0; q < 4; ++q)
        cv[q] = *reinterpret_cast<const float4*>(Cprev + base + 4 * q);
    }
    float o[16];
#pragma unroll
    for (int j = 0; j < 16; ++j) {
      float v = blk[i][j];
      if constexpr (MODE >= 1) {
        const float pj = (&cv[j >> 2].x)[j & 3];
        v = __fadd_rn(pj, v);               // ascending block merge
      }
      if constexpr (MODE == 2) {
        v = __fadd_rn(v, bs[j]);            // separate fp32 bias add
        o[j] = RELU ? (v > 0.0f ? v : 0.0f) : (v > 0.0f ? 1.0f : 0.0f);
      } else {
        o[j] = v;                           // fp32 partial, exact
      }
    }
#pragma unroll
    for (int q = 0; q < 4; ++q)
      *reinterpret_cast<float4*>(Cout + base + 4 * q) =
          make_float4(o[4 * q], o[4 * q + 1], o[4 * q + 2], o[4 * q + 3]);
  }
}

static void run_layer(const float* A, const float* W, const float* bias,
                      float* partial, float* dest, bool relu, int rows,
                      int N, int K, hipStream_t stream) {
  const dim3 blk(256);
  const dim3 g(N / BN, rows / BM);
  const int NP = K / KBLK;   // 8 passes
  for (int p = 0; p < NP; ++p) {
    const int k0 = p * KBLK;
    if (p == 0) {
      gemm_pass<0, false><<<g, blk, 0, stream>>>(A, W, bias, nullptr, partial,
                                                 N, K, k0);
    } else if (p < NP - 1) {
      gemm_pass<1, false><<<g, blk, 0, stream>>>(A, W, bias, partial, partial,
                                                 N, K, k0);
    } else if (relu) {
      gemm_pass<2, true><<<g, blk, 0, stream>>>(A, W, bias, partial, dest,
                                                N, K, k0);
    } else {
      gemm_pass<2, false><<<g, blk, 0, stream>>>(A, W, bias, partial, dest,
                                                 N, K, k0);
    }
  }
}

extern "C" void kernel_launch(void* const* d_in, const int* in_sizes, int n_in,
                              void* d_out, int out_size, void* d_ws, size_t ws_size,
                              hipStream_t stream) {
  const float* x  = (const float*)d_in[0];
  const float* W1 = (const float*)d_in[1];
  const float* b1 = (const float*)d_in[2];
  const float* W2 = (const float*)d_in[3];
  const float* b2 = (const float*)d_in[4];
  float* out = (float*)d_out;

  size_t rows = ws_size / ((size_t)2 * HID * sizeof(float));
  rows = (rows / BM) * BM;
  if (rows > (size_t)B_TOT) rows = B_TOT;
  if (rows < BM) rows = BM;

  float* h   = (float*)d_ws;                         // rows x HID
  float* y2p = h + (size_t)rows * HID;               // rows x OUT

  for (int m0 = 0; m0 < B_TOT; m0 += (int)rows) {
    const int mrows = (B_TOT - m0 < (int)rows) ? (B_TOT - m0) : (int)rows;
    run_layer(x + (size_t)m0 * IN, W1, b1, h, h, true, mrows, HID, IN, stream);
    run_layer(h, W2, b2, y2p, out + (size_t)m0 * OUT, false, mrows, OUT, HID,
              stream);
  }
}